// Round 13
// baseline (284.773 us; speedup 1.0000x reference)
//
#include <hip/hip_runtime.h>
#include <hip/hip_bf16.h>

// ChunkwiseRetentionMixer: state = x@Ws^T ; state = cumsum_L(state) ;
// out = rmsnorm(state)@Wo^T.  B=4, L=8192, H=1024, S=64, fp32 in/out.
//
// R12: F+K model probe. R10->R11 delta was -3us despite 2x occupancy ->
// kernels were already ~55us (HBM floor ~45us); dur_us dominated by ~220us
// fixed harness fills/restores. This round: drop k_prep (fold W split back
// into staging, bit-identical), keep all numerics frozen.
//   k_proj: 64x64x1024 triple-split bf16 MFMA GEMM -> state + chunk col-sums
//   k_scan: wave-shuffle scan of chunk sums -> exclusive offsets
//   k_out : in-chunk shuffle scan + rms + 64x1024x64 GEMM -> out

#define BB 4
#define LL 8192
#define HH 1024
#define SS 64
#define TL 64
#define CPB (LL / TL)          // 128 chunks per batch
#define NCHUNK (BB * CPB)      // 512
#define EPS 1.1920928955078125e-07f

typedef __attribute__((ext_vector_type(8))) short bf16x8;   // 8 bf16 = 4 VGPRs
typedef __attribute__((ext_vector_type(4))) float f32x4;    // MFMA accum

__device__ __forceinline__ short bf16h(float v) {
    __hip_bfloat16 b = __float2bfloat16(v);
    return __builtin_bit_cast(short, b);
}
__device__ __forceinline__ float bf16tof(short s) {
    __hip_bfloat16 b = __builtin_bit_cast(__hip_bfloat16, s);
    return __bfloat162float(b);
}

__device__ __forceinline__ void split3_8(const float* f, bf16x8& h8, bf16x8& m8, bf16x8& l8) {
    #pragma unroll
    for (int j = 0; j < 8; ++j) {
        const short hb = bf16h(f[j]);
        const float r1 = f[j] - bf16tof(hb);     // exact in fp32
        const short mb = bf16h(r1);
        const float r2 = r1 - bf16tof(mb);       // exact in fp32
        h8[j] = hb; m8[j] = mb; l8[j] = bf16h(r2);
    }
}

// 6-product accumulate: (h+m+l)*(h+m+l) keeping terms >= 2^-24 scale
#define MFMA6(ACC, AH, AM, AL, BH, BM, BL)                                        \
    ACC = __builtin_amdgcn_mfma_f32_16x16x32_bf16(AH, BH, ACC, 0, 0, 0);          \
    ACC = __builtin_amdgcn_mfma_f32_16x16x32_bf16(AH, BM, ACC, 0, 0, 0);          \
    ACC = __builtin_amdgcn_mfma_f32_16x16x32_bf16(AM, BH, ACC, 0, 0, 0);          \
    ACC = __builtin_amdgcn_mfma_f32_16x16x32_bf16(AH, BL, ACC, 0, 0, 0);          \
    ACC = __builtin_amdgcn_mfma_f32_16x16x32_bf16(AL, BH, ACC, 0, 0, 0);          \
    ACC = __builtin_amdgcn_mfma_f32_16x16x32_bf16(AM, BM, ACC, 0, 0, 0);

// ============================ k_proj ============================
// 512 threads = 8 waves; wave w -> rows wr*32..+31 (wr=w>>2), cols wc*16..+15.
// Staging map: thread t -> row t>>3, cols (t&7)*8..+7 (full 64x64, coalesced).
__global__ __launch_bounds__(512, 4) void k_proj(const float* __restrict__ x,
                                                 const float* __restrict__ Ws,
                                                 float* __restrict__ state,  // [c][l][s]
                                                 float* __restrict__ csum)   // [c][s]
{
    __shared__ __align__(16) short Ah[64][72], Am[64][72], Al[64][72];
    __shared__ __align__(16) short Bh[64][72], Bm[64][72], Bl[64][72];
    float (*red)[65] = (float(*)[65])Ah;    // overlay: used only after last K-tile

    const int tid = threadIdx.x;
    const int lane = tid & 63, w = tid >> 6;
    const int l16 = lane & 15, lg = lane >> 4;
    const int wr = w >> 2, wc = w & 3;
    const int c = blockIdx.x;
    const int arow = tid >> 3, acol8 = (tid & 7) * 8;
    const float* xp = x + (long)c * TL * HH;

    f32x4 acc[2] = {};
    float4 va[2], vb[2];
    va[0] = *(const float4*)(xp + (long)arow * HH + acol8);
    va[1] = *(const float4*)(xp + (long)arow * HH + acol8 + 4);
    vb[0] = *(const float4*)(Ws + (long)arow * HH + acol8);
    vb[1] = *(const float4*)(Ws + (long)arow * HH + acol8 + 4);

    for (int kt = 0; kt < HH; kt += 64) {
        {   // split both tiles fp32 -> 3 bf16 levels
            const float fa[8] = {va[0].x, va[0].y, va[0].z, va[0].w,
                                 va[1].x, va[1].y, va[1].z, va[1].w};
            const float fb[8] = {vb[0].x, vb[0].y, vb[0].z, vb[0].w,
                                 vb[1].x, vb[1].y, vb[1].z, vb[1].w};
            bf16x8 h8, m8, l8;
            split3_8(fa, h8, m8, l8);
            *(bf16x8*)&Ah[arow][acol8] = h8;
            *(bf16x8*)&Am[arow][acol8] = m8;
            *(bf16x8*)&Al[arow][acol8] = l8;
            split3_8(fb, h8, m8, l8);
            *(bf16x8*)&Bh[arow][acol8] = h8;
            *(bf16x8*)&Bm[arow][acol8] = m8;
            *(bf16x8*)&Bl[arow][acol8] = l8;
        }
        __syncthreads();                            // tiles ready
        if (kt + 64 < HH) {                         // prefetch next K-tile
            va[0] = *(const float4*)(xp + (long)arow * HH + kt + 64 + acol8);
            va[1] = *(const float4*)(xp + (long)arow * HH + kt + 64 + acol8 + 4);
            vb[0] = *(const float4*)(Ws + (long)arow * HH + kt + 64 + acol8);
            vb[1] = *(const float4*)(Ws + (long)arow * HH + kt + 64 + acol8 + 4);
        }
        #pragma unroll
        for (int ks = 0; ks < 2; ++ks) {
            const int ko = ks * 32 + lg * 8;
            bf16x8 ah[2], am[2], al[2];
            #pragma unroll
            for (int f = 0; f < 2; ++f) {
                const int ar = wr * 32 + f * 16 + l16;
                ah[f] = *(const bf16x8*)&Ah[ar][ko];
                am[f] = *(const bf16x8*)&Am[ar][ko];
                al[f] = *(const bf16x8*)&Al[ar][ko];
            }
            const int br = wc * 16 + l16;
            const bf16x8 bh = *(const bf16x8*)&Bh[br][ko];
            const bf16x8 bm = *(const bf16x8*)&Bm[br][ko];
            const bf16x8 bl = *(const bf16x8*)&Bl[br][ko];
            #pragma unroll
            for (int fi = 0; fi < 2; ++fi) {
                MFMA6(acc[fi], ah[fi], am[fi], al[fi], bh, bm, bl)
            }
        }
        __syncthreads();                            // tiles consumed
    }

    // epilogue: D row l = wr*32+fi*16+lg*4+r, col s = wc*16+l16
    float* sp = state + (long)c * (TL * SS);
    #pragma unroll
    for (int fi = 0; fi < 2; ++fi) {
        float part = 0.f;
        #pragma unroll
        for (int r = 0; r < 4; ++r) {
            const int l = wr * 32 + fi * 16 + lg * 4 + r;
            const int s = wc * 16 + l16;
            sp[l * SS + s] = acc[fi][r];
            part += acc[fi][r];
        }
        red[(wr * 2 + fi) * 4 + lg][wc * 16 + l16] = part;
    }
    __syncthreads();
    if (tid < 64) {
        float t = 0.f;
        #pragma unroll
        for (int g = 0; g < 16; ++g) t += red[g][tid];
        csum[(long)c * SS + tid] = t;
    }
}

// ============================ k_scan ============================
__global__ __launch_bounds__(256) void k_scan(const float* __restrict__ csum,
                                              float* __restrict__ off)
{
    const int tid = threadIdx.x;
    const int lane = tid & 63;
    const int wid = (blockIdx.x * 256 + tid) >> 6;  // 0..255
    const int b = wid >> 6, s = wid & 63;
    const long base = (long)b * CPB * SS + s;

    float i0 = csum[base + (long)lane * SS];
    float i1 = csum[base + (long)(lane + 64) * SS];
    #pragma unroll
    for (int d = 1; d < 64; d <<= 1) {
        float n = __shfl_up(i0, d, 64); if (lane >= d) i0 += n;
    }
    #pragma unroll
    for (int d = 1; d < 64; d <<= 1) {
        float n = __shfl_up(i1, d, 64); if (lane >= d) i1 += n;
    }
    float tot0 = __shfl(i0, 63, 64);
    float e0 = __shfl_up(i0, 1, 64); if (lane == 0) e0 = 0.f;
    float e1 = __shfl_up(i1, 1, 64); if (lane == 0) e1 = 0.f;
    e1 += tot0;
    off[base + (long)lane * SS] = e0;
    off[base + (long)(lane + 64) * SS] = e1;
}

// ============================ k_out ============================
__global__ __launch_bounds__(512, 4) void k_out(const float* __restrict__ state, // [c][l][s]
                                                const float* __restrict__ off,   // [c][s]
                                                const float* __restrict__ Wo,    // [h][s]
                                                float* __restrict__ out)         // [b][l][h]
{
    __shared__ __align__(16) short Ah[64][72], Am[64][72], Al[64][72];
    __shared__ __align__(16) char pool[64 * 72 * 2 * 3];   // 27648 B: B 3-tiles | st
    __shared__ float ssq[8][64];
    __shared__ float scale[64];
    float (*st)[65] = (float(*)[65])pool;                  // 16640 B, dies after Phase C
    short (*Bh)[72] = (short(*)[72])pool;
    short (*Bm)[72] = (short(*)[72])(pool + 64 * 72 * 2);
    short (*Bl)[72] = (short(*)[72])(pool + 64 * 72 * 4);

    const int tid = threadIdx.x;
    const int lane = tid & 63, w = tid >> 6;
    const int l16 = lane & 15, lg = lane >> 4;
    const int wr = w >> 2, wc = w & 3;
    const int c = blockIdx.x;
    const int arow = tid >> 3, acol8 = (tid & 7) * 8;

    // prefetch first Wo tile (fp32, split during staging)
    float4 vw[2];
    vw[0] = *(const float4*)(Wo + (long)arow * SS + acol8);
    vw[1] = *(const float4*)(Wo + (long)arow * SS + acol8 + 4);

    // Phase A: state tile -> st[l][s] (stride 65)
    const float* sp = state + (long)c * (TL * SS);
    #pragma unroll
    for (int i = 0; i < 2; ++i) {
        const int e = (i * 512 + tid) * 4;
        const int l = e >> 6, s = e & 63;
        const float4 v = *(const float4*)(sp + e);
        st[l][s] = v.x; st[l][s+1] = v.y; st[l][s+2] = v.z; st[l][s+3] = v.w;
    }
    __syncthreads();

    // Phase B: shuffle-scan along l (lane = l), wave w owns s = w*8..+7;
    // fused per-row sum-of-squares.
    float sq = 0.f;
    for (int i = 0; i < 8; ++i) {
        const int s = w * 8 + i;
        float v = st[lane][s];
        #pragma unroll
        for (int d = 1; d < 64; d <<= 1) {
            const float n = __shfl_up(v, d, 64);
            if (lane >= d) v += n;
        }
        v += off[(long)c * SS + s];
        st[lane][s] = v;
        sq = fmaf(v, v, sq);
    }
    ssq[w][lane] = sq;
    __syncthreads();
    if (tid < 64) {
        float t = 0.f;
        #pragma unroll
        for (int g = 0; g < 8; ++g) t += ssq[g][tid];
        scale[tid] = rsqrtf(t * (1.f / 64.f) + EPS);
    }
    __syncthreads();

    // Phase C: rms-scale rows, 3-level split to bf16 A-tiles (scale folded)
    {
        const int l = tid >> 3, s0 = (tid & 7) * 8;
        const float sc = scale[l];
        float f8[8];
        #pragma unroll
        for (int j = 0; j < 8; ++j) f8[j] = st[l][s0 + j] * sc;
        bf16x8 h8, m8, l8;
        split3_8(f8, h8, m8, l8);
        *(bf16x8*)&Ah[l][s0] = h8;
        *(bf16x8*)&Am[l][s0] = m8;
        *(bf16x8*)&Al[l][s0] = l8;
    }
    __syncthreads();                              // st dead; pool -> B tiles

    const int b = c / CPB;
    const int l0 = (c % CPB) * TL;
    float* op = out + ((long)b * LL + l0) * HH;

    for (int ht = 0; ht < HH; ht += 64) {
        {   // stage B tile: split fp32 Wo -> 3 bf16 levels
            const float fb[8] = {vw[0].x, vw[0].y, vw[0].z, vw[0].w,
                                 vw[1].x, vw[1].y, vw[1].z, vw[1].w};
            bf16x8 h8, m8, l8;
            split3_8(fb, h8, m8, l8);
            *(bf16x8*)&Bh[arow][acol8] = h8;
            *(bf16x8*)&Bm[arow][acol8] = m8;
            *(bf16x8*)&Bl[arow][acol8] = l8;
        }
        __syncthreads();                          // B tile ready
        if (ht + 64 < HH) {
            vw[0] = *(const float4*)(Wo + (long)(ht + 64 + arow) * SS + acol8);
            vw[1] = *(const float4*)(Wo + (long)(ht + 64 + arow) * SS + acol8 + 4);
        }
        f32x4 acc[2] = {};
        #pragma unroll
        for (int ks = 0; ks < 2; ++ks) {
            const int ko = ks * 32 + lg * 8;
            const int br = wc * 16 + l16;
            const bf16x8 bh = *(const bf16x8*)&Bh[br][ko];
            const bf16x8 bm = *(const bf16x8*)&Bm[br][ko];
            const bf16x8 bl = *(const bf16x8*)&Bl[br][ko];
            bf16x8 ah[2], am[2], al[2];
            #pragma unroll
            for (int f = 0; f < 2; ++f) {
                const int ar = wr * 32 + f * 16 + l16;
                ah[f] = *(const bf16x8*)&Ah[ar][ko];
                am[f] = *(const bf16x8*)&Am[ar][ko];
                al[f] = *(const bf16x8*)&Al[ar][ko];
            }
            #pragma unroll
            for (int fi = 0; fi < 2; ++fi) {
                MFMA6(acc[fi], ah[fi], am[fi], al[fi], bh, bm, bl)
            }
        }
        #pragma unroll
        for (int fi = 0; fi < 2; ++fi)
            #pragma unroll
            for (int r = 0; r < 4; ++r) {
                const int l = wr * 32 + fi * 16 + lg * 4 + r;
                const int h = wc * 16 + l16;
                op[(long)l * HH + ht + h] = acc[fi][r];
            }
        __syncthreads();                          // B tile consumed
    }
}

extern "C" void kernel_launch(void* const* d_in, const int* in_sizes, int n_in,
                              void* d_out, int out_size, void* d_ws, size_t ws_size,
                              hipStream_t stream) {
    const float* x  = (const float*)d_in[0];
    const float* Ws = (const float*)d_in[1];
    const float* Wo = (const float*)d_in[2];
    float* out = (float*)d_out;

    float* state = (float*)d_ws;                               // 8 MB
    float* csum  = state + (size_t)NCHUNK * SS * TL;           // 128 KB
    float* off   = csum + (size_t)NCHUNK * SS;                 // 128 KB

    k_proj<<<NCHUNK, 512, 0, stream>>>(x, Ws, state, csum);
    k_scan<<<64, 256, 0, stream>>>(csum, off);
    k_out<<<NCHUNK, 512, 0, stream>>>(state, off, Wo, out);
}